// Round 2
// baseline (474.492 us; speedup 1.0000x reference)
//
#include <hip/hip_runtime.h>
#include <hip/hip_bf16.h>
#include <stdint.h>

#define B_ 16
#define C_ 512
#define N_ 4096
#define KS_ 4              // split-K factor for the Gram GEMM

typedef float f32x4 __attribute__((ext_vector_type(4)));
typedef __bf16 bf16x8 __attribute__((ext_vector_type(8)));

// fp32 -> bf16 round-to-nearest-even
static __device__ __forceinline__ unsigned short f2bf(float f) {
    unsigned int u = __float_as_uint(f);
    u += 0x7fffu + ((u >> 16) & 1u);
    return (unsigned short)(u >> 16);
}

// pack float4 -> 4 bf16 (2 dwords) via v_cvt_pk_bf16_f32
static __device__ __forceinline__ uint2 f4_to_bf4(float4 v) {
    __hip_bfloat162 lo = __float22bfloat162_rn(make_float2(v.x, v.y));
    __hip_bfloat162 hi = __float22bfloat162_rn(make_float2(v.z, v.w));
    uint2 r;
    r.x = *reinterpret_cast<unsigned int*>(&lo);
    r.y = *reinterpret_cast<unsigned int*>(&hi);
    return r;
}

// async global->LDS, 16B per lane (global_load_lds_dwordx4)
static __device__ __forceinline__ void gload_lds16(const void* g, void* l) {
    __builtin_amdgcn_global_load_lds(
        (__attribute__((address_space(1))) unsigned int*)(g),
        (__attribute__((address_space(3))) unsigned int*)(l),
        16, 0, 0);
}

// ---------------------------------------------------------------------------
// Kernel 1: x (fp32, BxCxN) -> qt16 (bf16, BxNxC).  64x64 LDS-tiled transpose.
// Pad = 65 ushorts: transpose-read lane stride = 4*65*2 B = 130 words -> bank
// stride 2 -> conflict-free (old pad 72 gave 8-way).
// ---------------------------------------------------------------------------
__global__ __launch_bounds__(256)
void convert_transpose(const float* __restrict__ x,
                       unsigned short* __restrict__ qt16) {
    __shared__ unsigned short tile[64][65];
    int b  = blockIdx.z;
    int c0 = blockIdx.y * 64, n0 = blockIdx.x * 64;
    int tx = threadIdx.x & 15, ty = threadIdx.x >> 4;

    const float*    xb  = x    + ((size_t)b * C_ + c0) * N_ + n0;
    unsigned short* qtb = qt16 + ((size_t)b * N_ + n0) * C_ + c0;

#pragma unroll
    for (int s = 0; s < 4; ++s) {
        int rr = s * 16 + ty;
        float4 v = *(const float4*)(xb + (size_t)rr * N_ + tx * 4);
        tile[rr][tx * 4 + 0] = f2bf(v.x);
        tile[rr][tx * 4 + 1] = f2bf(v.y);
        tile[rr][tx * 4 + 2] = f2bf(v.z);
        tile[rr][tx * 4 + 3] = f2bf(v.w);
    }
    __syncthreads();
#pragma unroll
    for (int s = 0; s < 4; ++s) {
        int nr = s * 16 + ty;
        ushort4 p;
        p.x = tile[tx * 4 + 0][nr];
        p.y = tile[tx * 4 + 1][nr];
        p.z = tile[tx * 4 + 2][nr];
        p.w = tile[tx * 4 + 3][nr];
        *(ushort4*)(qtb + (size_t)nr * C_ + tx * 4) = p;
    }
}

// ---------------------------------------------------------------------------
// Kernel 2: partial Gram. epart[ks][b] = X[b][:, ks-slice] . X^T  (fp32 out)
// Reads x fp32 directly, converts to bf16 while staging into LDS (VGPR path).
// Split-K=4 -> grid 4x4x64 = 1024 blocks = 4/CU.
// Partial Gram is symmetric -> store accumulator transposed = float4 stores.
// ---------------------------------------------------------------------------
__global__ __launch_bounds__(256)
void gemm_gram_splitk(const float* __restrict__ x, float* __restrict__ epart) {
    int bz = blockIdx.z;
    int b = bz >> 2, ks = bz & 3;
    const int Kc = N_ / KS_;                       // 1024
    const float* Xb = x + (size_t)b * C_ * N_ + (size_t)ks * Kc;
    int m0 = blockIdx.y * 128, n0 = blockIdx.x * 128;

    __shared__ unsigned short As[128 * 32];
    __shared__ unsigned short Bs[128 * 32];

    int t = threadIdx.x;
    int lane = t & 63, wave = t >> 6;
    int wm = (wave >> 1) * 64, wn = (wave & 1) * 64;
    int qd = lane >> 4, r = lane & 15;

    f32x4 acc[4][4] = {};

    for (int k0 = 0; k0 < Kc; k0 += 32) {
        __syncthreads();
#pragma unroll
        for (int p = 0; p < 4; ++p) {
            int e = (p * 256 + t) * 4;             // element idx in 128x32 tile
            int row = e >> 5, col = e & 31;
            float4 va = *(const float4*)(Xb + (size_t)(m0 + row) * N_ + k0 + col);
            float4 vb = *(const float4*)(Xb + (size_t)(n0 + row) * N_ + k0 + col);
            *(uint2*)&As[row * 32 + col] = f4_to_bf4(va);
            *(uint2*)&Bs[row * 32 + col] = f4_to_bf4(vb);
        }
        __syncthreads();

        bf16x8 af[4], bfr[4];
#pragma unroll
        for (int i = 0; i < 4; ++i)
            af[i] = *(const bf16x8*)&As[(wm + i * 16 + r) * 32 + qd * 8];
#pragma unroll
        for (int j = 0; j < 4; ++j)
            bfr[j] = *(const bf16x8*)&Bs[(wn + j * 16 + r) * 32 + qd * 8];
#pragma unroll
        for (int i = 0; i < 4; ++i)
#pragma unroll
            for (int j = 0; j < 4; ++j)
                acc[i][j] = __builtin_amdgcn_mfma_f32_16x16x32_bf16(af[i], bfr[j], acc[i][j], 0, 0, 0);
    }

    // partial Gram is symmetric: store D[c,d] at [d,c] -> contiguous float4
    float* Db = epart + (size_t)(ks * B_ + b) * C_ * C_;
#pragma unroll
    for (int i = 0; i < 4; ++i)
#pragma unroll
        for (int j = 0; j < 4; ++j) {
            int cbase = m0 + wm + i * 16 + qd * 4;  // 4 consecutive c (acc regs)
            int d     = n0 + wn + j * 16 + r;
            *(f32x4*)(Db + (size_t)d * C_ + cbase) = acc[i][j];
        }
}

// ---------------------------------------------------------------------------
// Kernel 3: attention = softmax(-sum_s epart[s]), row-wise; bf16 out.
// ---------------------------------------------------------------------------
__global__ __launch_bounds__(256)
void softmax_neg4(const float* __restrict__ epart, unsigned short* __restrict__ att) {
    size_t row = blockIdx.x;                       // b*C + c
    const size_t slice = (size_t)B_ * C_ * C_;
    const float* e = epart + row * C_;
    int t = threadIdx.x;

    float e0 = 0.f, e1 = 0.f;
#pragma unroll
    for (int s = 0; s < KS_; ++s) {
        e0 += e[s * slice + t];
        e1 += e[s * slice + t + 256];
    }
    float m = fminf(e0, e1);                       // min(e) == -max(-e)
#pragma unroll
    for (int off = 32; off > 0; off >>= 1) m = fminf(m, __shfl_down(m, off, 64));
    __shared__ float red[8];
    if ((t & 63) == 0) red[t >> 6] = m;
    __syncthreads();
    m = fminf(fminf(red[0], red[1]), fminf(red[2], red[3]));

    float p0 = __expf(m - e0), p1 = __expf(m - e1);
    float s = p0 + p1;
#pragma unroll
    for (int off = 32; off > 0; off >>= 1) s += __shfl_down(s, off, 64);
    if ((t & 63) == 0) red[4 + (t >> 6)] = s;
    __syncthreads();
    s = red[4] + red[5] + red[6] + red[7];
    float inv = 1.0f / s;

    att[row * C_ + t]       = f2bf(p0 * inv);
    att[row * C_ + t + 256] = f2bf(p1 * inv);
}

// ---------------------------------------------------------------------------
// Kernel 4: y = gamma*(att . Q) + x, computed TRANSPOSED:
//   D[n, c] = sum_d qt[n,d] * att[c,d]  == out[c,n]
// A = qt16 (M=n, K-contig), B = att (N=c, K-contig) -> same bt structure, but
// each lane's 4 acc regs are consecutive n -> float4 epilogue load/store.
// ---------------------------------------------------------------------------
__global__ __launch_bounds__(256)
void gemm_out_t(const unsigned short* __restrict__ att,
                const unsigned short* __restrict__ qt16,
                const float* __restrict__ x,
                const float* __restrict__ gamma,
                float* __restrict__ y) {
    const int K = C_;                               // 512
    int b = blockIdx.z;
    const unsigned short* Ab = qt16 + (size_t)b * N_ * C_;   // rows n, contig d
    const unsigned short* Bb = att  + (size_t)b * C_ * C_;   // rows c, contig d
    int m0 = blockIdx.x * 128;                      // n dim (32 tiles)
    int n0 = blockIdx.y * 128;                      // c dim (4 tiles)

    __shared__ unsigned short As[128 * 32];
    __shared__ unsigned short Bs[128 * 32];

    int t = threadIdx.x;
    int lane = t & 63, wave = t >> 6;
    int wm = (wave >> 1) * 64, wn = (wave & 1) * 64;
    int qd = lane >> 4, r = lane & 15;

    f32x4 acc[4][4] = {};

    for (int k0 = 0; k0 < K; k0 += 32) {
        __syncthreads();
#pragma unroll
        for (int i = 0; i < 2; ++i) {
            int o = (i * 256 + t) * 16;             // LDS byte offset
            int mrow = o >> 6, inrow = o & 63;      // 64 B per 32-elem bf16 row
            gload_lds16((const char*)Ab + (size_t)(m0 + mrow) * (K * 2) + k0 * 2 + inrow,
                        (char*)As + o);
            gload_lds16((const char*)Bb + (size_t)(n0 + mrow) * (K * 2) + k0 * 2 + inrow,
                        (char*)Bs + o);
        }
        __syncthreads();

        bf16x8 af[4], bfr[4];
#pragma unroll
        for (int i = 0; i < 4; ++i)
            af[i] = *(const bf16x8*)&As[(wm + i * 16 + r) * 32 + qd * 8];
#pragma unroll
        for (int j = 0; j < 4; ++j)
            bfr[j] = *(const bf16x8*)&Bs[(wn + j * 16 + r) * 32 + qd * 8];
#pragma unroll
        for (int i = 0; i < 4; ++i)
#pragma unroll
            for (int j = 0; j < 4; ++j)
                acc[i][j] = __builtin_amdgcn_mfma_f32_16x16x32_bf16(af[i], bfr[j], acc[i][j], 0, 0, 0);
    }

    float g = gamma[0];
    const float* xb = x + (size_t)b * C_ * N_;
    float*       yb = y + (size_t)b * C_ * N_;
#pragma unroll
    for (int i = 0; i < 4; ++i)
#pragma unroll
        for (int j = 0; j < 4; ++j) {
            int nbase = m0 + wm + i * 16 + qd * 4;  // 4 consecutive n
            int c     = n0 + wn + j * 16 + r;
            size_t idx = (size_t)c * N_ + nbase;
            float4 xv = *(const float4*)(xb + idx);
            f32x4 a = acc[i][j];
            float4 o;
            o.x = g * a[0] + xv.x;
            o.y = g * a[1] + xv.y;
            o.z = g * a[2] + xv.z;
            o.w = g * a[3] + xv.w;
            *(float4*)(yb + idx) = o;
        }
}

// ---------------------------------------------------------------------------
// Workspace layout (bytes), total 142,606,336 (< known-safe 159.4 MB):
//   qt16  @ 0          : 67,108,864
//   att16 @ 67,108,864 :  8,388,608
//   epart @ 75,497,472 : 4 x 16,777,216 = 67,108,864
// ---------------------------------------------------------------------------
extern "C" void kernel_launch(void* const* d_in, const int* in_sizes, int n_in,
                              void* d_out, int out_size, void* d_ws, size_t ws_size,
                              hipStream_t stream) {
    const float* x     = (const float*)d_in[0];
    const float* gamma = (const float*)d_in[1];
    float*       y     = (float*)d_out;

    char* ws = (char*)d_ws;
    unsigned short* qt16  = (unsigned short*)(ws);
    unsigned short* att16 = (unsigned short*)(ws + 67108864);
    float*          epart = (float*)(ws + 75497472);

    convert_transpose<<<dim3(N_ / 64, C_ / 64, B_), dim3(256), 0, stream>>>(x, qt16);
    gemm_gram_splitk<<<dim3(C_ / 128, C_ / 128, B_ * KS_), dim3(256), 0, stream>>>(x, epart);
    softmax_neg4<<<dim3(B_ * C_), dim3(256), 0, stream>>>(epart, att16);
    gemm_out_t<<<dim3(N_ / 128, C_ / 128, B_), dim3(256), 0, stream>>>(att16, qt16, x, gamma, y);
}

// Round 3
// 420.857 us; speedup vs baseline: 1.1274x; 1.1274x over previous
//
#include <hip/hip_runtime.h>
#include <hip/hip_bf16.h>
#include <stdint.h>

#define B_ 16
#define C_ 512
#define N_ 4096
#define KS_ 4              // split-K factor for the Gram GEMM

typedef float f32x4 __attribute__((ext_vector_type(4)));
typedef __bf16 bf16x8 __attribute__((ext_vector_type(8)));

// fp32 -> bf16 round-to-nearest-even
static __device__ __forceinline__ unsigned short f2bf(float f) {
    unsigned int u = __float_as_uint(f);
    u += 0x7fffu + ((u >> 16) & 1u);
    return (unsigned short)(u >> 16);
}

// async global->LDS, 16B per lane (global_load_lds_dwordx4)
static __device__ __forceinline__ void gload_lds16(const void* g, void* l) {
    __builtin_amdgcn_global_load_lds(
        (__attribute__((address_space(1))) unsigned int*)(g),
        (__attribute__((address_space(3))) unsigned int*)(l),
        16, 0, 0);
}

// ---------------------------------------------------------------------------
// Kernel 1: x (fp32, BxCxN) -> q16 (bf16, BxCxN) AND qt16 (bf16, BxNxC).
// 64x64 LDS tile for the transpose; pad 65 keeps transpose reads conflict-lite.
// ---------------------------------------------------------------------------
__global__ __launch_bounds__(256)
void convert_transpose(const float* __restrict__ x,
                       unsigned short* __restrict__ q16,
                       unsigned short* __restrict__ qt16) {
    __shared__ unsigned short tile[64][65];
    int b  = blockIdx.z;
    int c0 = blockIdx.y * 64, n0 = blockIdx.x * 64;
    int tx = threadIdx.x & 15, ty = threadIdx.x >> 4;

    const float*    xb  = x    + ((size_t)b * C_ + c0) * N_ + n0;
    unsigned short* qb  = q16  + ((size_t)b * C_ + c0) * N_ + n0;
    unsigned short* qtb = qt16 + ((size_t)b * N_ + n0) * C_ + c0;

#pragma unroll
    for (int s = 0; s < 4; ++s) {
        int rr = s * 16 + ty;
        float4 v = *(const float4*)(xb + (size_t)rr * N_ + tx * 4);
        unsigned short h0 = f2bf(v.x), h1 = f2bf(v.y), h2 = f2bf(v.z), h3 = f2bf(v.w);
        tile[rr][tx * 4 + 0] = h0;
        tile[rr][tx * 4 + 1] = h1;
        tile[rr][tx * 4 + 2] = h2;
        tile[rr][tx * 4 + 3] = h3;
        ushort4 p; p.x = h0; p.y = h1; p.z = h2; p.w = h3;
        *(ushort4*)(qb + (size_t)rr * N_ + tx * 4) = p;
    }
    __syncthreads();
#pragma unroll
    for (int s = 0; s < 4; ++s) {
        int nr = s * 16 + ty;
        ushort4 p;
        p.x = tile[tx * 4 + 0][nr];
        p.y = tile[tx * 4 + 1][nr];
        p.z = tile[tx * 4 + 2][nr];
        p.w = tile[tx * 4 + 3][nr];
        *(ushort4*)(qtb + (size_t)nr * C_ + tx * 4) = p;
    }
}

// ---------------------------------------------------------------------------
// Kernel 2: partial Gram from bf16 q16, split-K.
//   epart[ks][b] = Q[b][:, ks*1024 : (ks+1)*1024] . Q^T   (fp32)
// m97 structure: 128x128 tile, BK=32, global_load_lds width 16.
// Grid 4x4x(16*4) = 1024 blocks = 4/CU. Per (b,ks) all 16 blocks share a
// 1 MB q16 slice -> L2-resident re-reads.
// Partial Gram is symmetric -> store accumulator transposed = float4 stores.
// ---------------------------------------------------------------------------
__global__ __launch_bounds__(256)
void gemm_gram_splitk(const unsigned short* __restrict__ q16,
                      float* __restrict__ epart) {
    int bz = blockIdx.z;
    int b = bz >> 2, ks = bz & 3;
    const int Kc = N_ / KS_;                           // 1024
    const char* Qb = (const char*)(q16 + (size_t)b * C_ * N_) + (size_t)ks * Kc * 2;
    const int row_bytes = N_ * 2;                      // full K row stride (8192 B)
    int m0 = blockIdx.y * 128, n0 = blockIdx.x * 128;

    __shared__ unsigned short As[128 * 32];
    __shared__ unsigned short Bs[128 * 32];

    int t = threadIdx.x;
    int lane = t & 63, wave = t >> 6;
    int wm = (wave >> 1) * 64, wn = (wave & 1) * 64;
    int qd = lane >> 4, r = lane & 15;

    f32x4 acc[4][4] = {};

    for (int k0 = 0; k0 < Kc; k0 += 32) {
        __syncthreads();
#pragma unroll
        for (int i = 0; i < 2; ++i) {
            int o = (i * 256 + t) * 16;                // LDS byte offset
            int mrow = o >> 6, inrow = o & 63;         // 64 B per 32-elem bf16 row
            gload_lds16(Qb + (size_t)(m0 + mrow) * row_bytes + k0 * 2 + inrow,
                        (char*)As + o);
            gload_lds16(Qb + (size_t)(n0 + mrow) * row_bytes + k0 * 2 + inrow,
                        (char*)Bs + o);
        }
        __syncthreads();

        bf16x8 af[4], bfr[4];
#pragma unroll
        for (int i = 0; i < 4; ++i)
            af[i] = *(const bf16x8*)&As[(wm + i * 16 + r) * 32 + qd * 8];
#pragma unroll
        for (int j = 0; j < 4; ++j)
            bfr[j] = *(const bf16x8*)&Bs[(wn + j * 16 + r) * 32 + qd * 8];
#pragma unroll
        for (int i = 0; i < 4; ++i)
#pragma unroll
            for (int j = 0; j < 4; ++j)
                acc[i][j] = __builtin_amdgcn_mfma_f32_16x16x32_bf16(af[i], bfr[j], acc[i][j], 0, 0, 0);
    }

    // symmetric: store D[c,d] at [d,c] -> contiguous float4 stores
    float* Db = epart + (size_t)(ks * B_ + b) * C_ * C_;
#pragma unroll
    for (int i = 0; i < 4; ++i)
#pragma unroll
        for (int j = 0; j < 4; ++j) {
            int cbase = m0 + wm + i * 16 + qd * 4;     // 4 consecutive c (acc regs)
            int d     = n0 + wn + j * 16 + r;
            *(f32x4*)(Db + (size_t)d * C_ + cbase) = acc[i][j];
        }
}

// ---------------------------------------------------------------------------
// Kernel 3: attention = softmax(-sum_s epart[s]), row-wise; bf16 out.
// ---------------------------------------------------------------------------
__global__ __launch_bounds__(256)
void softmax_neg4(const float* __restrict__ epart, unsigned short* __restrict__ att) {
    size_t row = blockIdx.x;                           // b*C + c
    const size_t slice = (size_t)B_ * C_ * C_;
    const float* e = epart + row * C_;
    int t = threadIdx.x;

    float e0 = 0.f, e1 = 0.f;
#pragma unroll
    for (int s = 0; s < KS_; ++s) {
        e0 += e[s * slice + t];
        e1 += e[s * slice + t + 256];
    }
    float m = fminf(e0, e1);                           // min(e) == -max(-e)
#pragma unroll
    for (int off = 32; off > 0; off >>= 1) m = fminf(m, __shfl_down(m, off, 64));
    __shared__ float red[8];
    if ((t & 63) == 0) red[t >> 6] = m;
    __syncthreads();
    m = fminf(fminf(red[0], red[1]), fminf(red[2], red[3]));

    float p0 = __expf(m - e0), p1 = __expf(m - e1);
    float s = p0 + p1;
#pragma unroll
    for (int off = 32; off > 0; off >>= 1) s += __shfl_down(s, off, 64);
    if ((t & 63) == 0) red[4 + (t >> 6)] = s;
    __syncthreads();
    s = red[4] + red[5] + red[6] + red[7];
    float inv = 1.0f / s;

    att[row * C_ + t]       = f2bf(p0 * inv);
    att[row * C_ + t + 256] = f2bf(p1 * inv);
}

// ---------------------------------------------------------------------------
// Kernel 4: y = gamma*(att . Q) + x, computed TRANSPOSED:
//   D[n, c] = sum_d qt[n,d] * att[c,d]  == out[c,n]
// Each lane's 4 acc regs are consecutive n -> float4 epilogue load/store.
// Overwrites d_out (which held epart) last.
// ---------------------------------------------------------------------------
__global__ __launch_bounds__(256)
void gemm_out_t(const unsigned short* __restrict__ att,
                const unsigned short* __restrict__ qt16,
                const float* __restrict__ x,
                const float* __restrict__ gamma,
                float* __restrict__ y) {
    const int K = C_;                                  // 512
    int b = blockIdx.z;
    const unsigned short* Ab = qt16 + (size_t)b * N_ * C_;   // rows n, contig d
    const unsigned short* Bb = att  + (size_t)b * C_ * C_;   // rows c, contig d
    int m0 = blockIdx.x * 128;                         // n
    int n0 = blockIdx.y * 128;                         // c

    __shared__ unsigned short As[128 * 32];
    __shared__ unsigned short Bs[128 * 32];

    int t = threadIdx.x;
    int lane = t & 63, wave = t >> 6;
    int wm = (wave >> 1) * 64, wn = (wave & 1) * 64;
    int qd = lane >> 4, r = lane & 15;

    f32x4 acc[4][4] = {};

    for (int k0 = 0; k0 < K; k0 += 32) {
        __syncthreads();
#pragma unroll
        for (int i = 0; i < 2; ++i) {
            int o = (i * 256 + t) * 16;
            int mrow = o >> 6, inrow = o & 63;
            gload_lds16((const char*)Ab + (size_t)(m0 + mrow) * (K * 2) + k0 * 2 + inrow,
                        (char*)As + o);
            gload_lds16((const char*)Bb + (size_t)(n0 + mrow) * (K * 2) + k0 * 2 + inrow,
                        (char*)Bs + o);
        }
        __syncthreads();

        bf16x8 af[4], bfr[4];
#pragma unroll
        for (int i = 0; i < 4; ++i)
            af[i] = *(const bf16x8*)&As[(wm + i * 16 + r) * 32 + qd * 8];
#pragma unroll
        for (int j = 0; j < 4; ++j)
            bfr[j] = *(const bf16x8*)&Bs[(wn + j * 16 + r) * 32 + qd * 8];
#pragma unroll
        for (int i = 0; i < 4; ++i)
#pragma unroll
            for (int j = 0; j < 4; ++j)
                acc[i][j] = __builtin_amdgcn_mfma_f32_16x16x32_bf16(af[i], bfr[j], acc[i][j], 0, 0, 0);
    }

    float g = gamma[0];
    const float* xb = x + (size_t)b * C_ * N_;
    float*       yb = y + (size_t)b * C_ * N_;
#pragma unroll
    for (int i = 0; i < 4; ++i)
#pragma unroll
        for (int j = 0; j < 4; ++j) {
            int nbase = m0 + wm + i * 16 + qd * 4;     // 4 consecutive n
            int c     = n0 + wn + j * 16 + r;
            size_t idx = (size_t)c * N_ + nbase;
            float4 xv = *(const float4*)(xb + idx);
            f32x4 a = acc[i][j];
            float4 o;
            o.x = g * a[0] + xv.x;
            o.y = g * a[1] + xv.y;
            o.z = g * a[2] + xv.z;
            o.w = g * a[3] + xv.w;
            *(float4*)(yb + idx) = o;
        }
}

// ---------------------------------------------------------------------------
// Workspace (142,606,336 B total, < proven-safe 159.4 MB):
//   q16   @ 0          : 67,108,864
//   qt16  @ 67,108,864 : 67,108,864
//   att16 @ 134,217,728:  8,388,608
// epart (4 x 16 x 512 x 512 fp32 = 67,108,864 B) lives in d_out (134 MB),
// which is dead until gemm_out_t overwrites it at the end.
// ---------------------------------------------------------------------------
extern "C" void kernel_launch(void* const* d_in, const int* in_sizes, int n_in,
                              void* d_out, int out_size, void* d_ws, size_t ws_size,
                              hipStream_t stream) {
    const float* x     = (const float*)d_in[0];
    const float* gamma = (const float*)d_in[1];
    float*       y     = (float*)d_out;

    char* ws = (char*)d_ws;
    unsigned short* q16   = (unsigned short*)(ws);
    unsigned short* qt16  = (unsigned short*)(ws + 67108864);
    unsigned short* att16 = (unsigned short*)(ws + 134217728);
    float*          epart = (float*)d_out;             // scratch until final GEMM

    convert_transpose<<<dim3(N_ / 64, C_ / 64, B_), dim3(256), 0, stream>>>(x, q16, qt16);
    gemm_gram_splitk<<<dim3(C_ / 128, C_ / 128, B_ * KS_), dim3(256), 0, stream>>>(q16, epart);
    softmax_neg4<<<dim3(B_ * C_), dim3(256), 0, stream>>>(epart, att16);
    gemm_out_t<<<dim3(N_ / 128, C_ / 128, B_), dim3(256), 0, stream>>>(att16, qt16, x, gamma, y);
}